// Round 17
// baseline (257.180 us; speedup 1.0000x reference)
//
#include <hip/hip_runtime.h>
#include <cstdint>
#include <cstddef>

#define NLV 5
#define NIMG 4
#define NSEL 4507          // 1000+1000+1000+1000+507 selected per image
#define TSEL (NIMG * NSEL)
#define POSTN 1000
#define TCAP 8192          // boundary-bin candidate cap
#define TTCAP 2048         // sub-boundary (tie-of-tie) cap
#define NHB 16             // sub-histograms per (image,level)
#define PBLK 64            // k_pick blocks per (image,level)
#define PCH 2048           // max elems per k_pick block (float4 grid-stride)

__device__ const int d_W[NLV]    = {200, 100, 50, 25, 13};
__device__ const int d_NL[NLV]   = {120000, 30000, 7500, 1875, 507};
__device__ const int d_KOFF[6]   = {0, 120000, 150000, 157500, 159375, 159882};
__device__ const int d_LOFF[6]   = {0, 1000, 2000, 3000, 4000, 4507};
__device__ const int d_KL[NLV]   = {1000, 1000, 1000, 1000, 507};

struct Ptrs {
    const float* obj[NLV];
    const float* del[NLV];
    const float* anch;
};

// order-preserving map: dk ascending <=> float descending
__device__ inline unsigned int dkey_of(float f) {
    unsigned int u = __float_as_uint(f);
    unsigned int mk = (u & 0x80000000u) ? ~u : (u | 0x80000000u);
    return ~mk;
}
__device__ inline float logit_from_dkey(unsigned int dk) {
    unsigned int mk = ~dk;
    unsigned int u = (mk & 0x80000000u) ? (mk & 0x7fffffffu) : ~mk;
    return __uint_as_float(u);
}

// ---- top-k stage 1+2: float4 LDS histograms; LAST block scans+thresholds ---
// Round-16 lesson: 256-thr blocks + scalar loads = 1 wave/SIMD, 30 serial
// load->atomic iterations, pure latency (51us). 1024 threads + float4
// grid-stride (levels 0-2; per-image bases are 16B-aligned) quadruples both
// wave count and bytes per vmem op.
__global__ __launch_bounds__(1024) void k_hist(Ptrs P, unsigned int* hist,
                                               unsigned int* hcnt,
                                               unsigned int* thr, int* scnt, int* tcnt) {
    int l = blockIdx.y, n = blockIdx.z;
    int nl_sz = d_NL[l];
    if (d_KL[l] >= nl_sz) return;            // level 4: all selected
    int nlid = n * NLV + l;
    int tid = threadIdx.x;
    __shared__ unsigned int h[2048];
    __shared__ unsigned int s_rank;
    __shared__ unsigned int wpre[16];
    h[tid] = 0; h[tid + 1024] = 0;
    __syncthreads();
    const float* ob = P.obj[l] + (size_t)n * nl_sz;
    if (l < 3) {                             // nl_sz%4==0, base 16B-aligned
        const float4* ob4 = (const float4*)ob;
        int q4 = nl_sz >> 2;
        for (int i = blockIdx.x * 1024 + tid; i < q4; i += NHB * 1024) {
            float4 v = ob4[i];
            atomicAdd(&h[dkey_of(v.x) >> 21], 1u);
            atomicAdd(&h[dkey_of(v.y) >> 21], 1u);
            atomicAdd(&h[dkey_of(v.z) >> 21], 1u);
            atomicAdd(&h[dkey_of(v.w) >> 21], 1u);
        }
    } else {                                 // level 3: tiny, scalar chunk
        int chunk = (nl_sz + NHB - 1) / NHB;
        int beg = blockIdx.x * chunk;
        int end = min(beg + chunk, nl_sz);
        for (int t = beg + tid; t < end; t += 1024)
            atomicAdd(&h[dkey_of(ob[t]) >> 21], 1u);
    }
    __syncthreads();
    unsigned int* outp = hist + ((size_t)nlid * NHB + blockIdx.x) * 2048;
    outp[tid] = h[tid]; outp[tid + 1024] = h[tid + 1024];
    __threadfence();                         // release sub-hist
    if (tid == 0) s_rank = atomicAdd(&hcnt[nlid], 1u);
    __syncthreads();
    if (s_rank != NHB - 1) return;
    __threadfence();                         // acquire all sub-hists

    // ---- thresh phase (1024 threads, 2 bins/thread pair scan) ----
    if (tid == 0) { scnt[nlid] = 0; tcnt[nlid] = 0; }
    int w = tid >> 6, lane = tid & 63;
    const unsigned int* hb = hist + (size_t)nlid * NHB * 2048;
    unsigned int v0 = 0, v1 = 0;
    #pragma unroll
    for (int sh = 0; sh < NHB; ++sh) {
        v0 += hb[sh * 2048 + 2 * tid];
        v1 += hb[sh * 2048 + 2 * tid + 1];
    }
    unsigned int s = v0 + v1;
    unsigned int ps = s;
    #pragma unroll
    for (int d = 1; d < 64; d <<= 1) {
        unsigned int t2 = (unsigned int)__shfl_up((int)ps, d, 64);
        if (lane >= d) ps += t2;
    }
    if (lane == 63) wpre[w] = ps;
    __syncthreads();
    unsigned int base = 0;
    #pragma unroll
    for (int ww = 0; ww < 16; ++ww) if (ww < w) base += wpre[ww];
    unsigned int incl = base + ps;           // inclusive prefix over PAIRS
    unsigned int target = (unsigned int)d_KL[l];
    unsigned int exc0 = incl - s, inc0 = incl - v1;
    unsigned int exc1 = inc0,    inc1 = incl;
    if (exc0 < target && target <= inc0) { thr[nlid * 2] = 2 * tid;     thr[nlid * 2 + 1] = exc0; }
    if (exc1 < target && target <= inc1) { thr[nlid * 2] = 2 * tid + 1; thr[nlid * 2 + 1] = exc1; }
}

// ---- top-k stage 3: pick winners, float4 loads, block-aggregated atomics ---
// LEAN kernel (32KB LDS, round-15 lesson). Levels 0-2 float4 grid-stride;
// per-block element count <= 2048 (PCH). Levels 3-4 scalar chunked.
__global__ __launch_bounds__(256) void k_pick(Ptrs P, const unsigned int* thr,
                                              int* scnt, int* tcnt,
                                              int* cg, float* cl,
                                              unsigned long long* tiebuf) {
    int l = blockIdx.y, n = blockIdx.z;
    int nl_sz = d_NL[l], kl = d_KL[l];
    int nlid = n * NLV + l;
    const float* ob = P.obj[l] + (size_t)n * nl_sz;
    int cbase = n * NSEL + d_LOFF[l];
    int koff = d_KOFF[l];
    int Wl = d_W[l], HW = Wl * Wl;
    int tid = threadIdx.x;

    if (kl >= nl_sz) {                       // level 4: deterministic slots
        int chunk = (nl_sz + PBLK - 1) / PBLK;
        int beg = blockIdx.x * chunk;
        int end = min(beg + chunk, nl_sz);
        for (int t = beg + tid; t < end; t += 256) {
            int a = t / HW, rem = t - a * HW;
            int p = rem * 3 + a;
            cg[cbase + p] = koff + p;
            cl[cbase + p] = ob[t];
        }
        return;
    }
    __shared__ int sp[PCH];
    __shared__ float sl[PCH];
    __shared__ unsigned long long tb[PCH];
    __shared__ int nsel, ntie, sbase, tbase;
    if (tid == 0) { nsel = 0; ntie = 0; }
    __syncthreads();

    unsigned int b0 = thr[nlid * 2];
    auto process = [&](float lg, int t) {
        unsigned int dk = dkey_of(lg);
        unsigned int bin = dk >> 21;
        if (bin < b0) {
            int pos = atomicAdd(&nsel, 1);   // LDS atomic
            int a = t / HW, rem = t - a * HW;
            sp[pos] = rem * 3 + a;
            sl[pos] = lg;
        } else if (bin == b0) {
            int pos = atomicAdd(&ntie, 1);   // LDS atomic
            int a = t / HW, rem = t - a * HW;
            tb[pos] = ((unsigned long long)dk << 17) |
                      (unsigned long long)(unsigned int)(rem * 3 + a);
        }
    };
    if (l < 3) {                             // float4 grid-stride
        const float4* ob4 = (const float4*)ob;
        int q4 = nl_sz >> 2;
        for (int i = blockIdx.x * 256 + tid; i < q4; i += PBLK * 256) {
            float4 v = ob4[i];
            int t0 = i * 4;
            process(v.x, t0);
            process(v.y, t0 + 1);
            process(v.z, t0 + 2);
            process(v.w, t0 + 3);
        }
    } else {                                 // level 3: scalar chunked
        int chunk = (nl_sz + PBLK - 1) / PBLK;
        int beg = blockIdx.x * chunk;
        int end = min(beg + chunk, nl_sz);
        for (int t = beg + tid; t < end; t += 256)
            process(ob[t], t);
    }
    __syncthreads();
    if (tid == 0) {
        sbase = atomicAdd(&scnt[nlid], nsel);  // 1 global atomic / block
        tbase = atomicAdd(&tcnt[nlid], ntie);
    }
    __syncthreads();
    int ns = nsel, nt = ntie, sb = sbase, tbs = tbase;
    for (int i = tid; i < ns; i += 256) {
        cg[cbase + sb + i] = koff + sp[i];
        cl[cbase + sb + i] = sl[i];
    }
    for (int i = tid; i < nt; i += 256) {
        int slot = tbs + i;
        if (slot < TCAP) tiebuf[(size_t)nlid * TCAP + slot] = tb[i];
    }
}

// ---- top-k stage 4: boundary candidates, radix-refined (own dispatch) ------
__global__ __launch_bounds__(1024) void k_tie(const unsigned int* thr, const int* tcnt,
                                              const unsigned long long* tiebuf,
                                              int* cg, float* cl) {
    int nlid = blockIdx.x;
    int n = nlid / NLV, l = nlid % NLV;
    if (d_KL[l] >= d_NL[l]) return;
    __shared__ unsigned long long kk[TCAP];
    __shared__ unsigned long long tt[TTCAP];
    __shared__ unsigned int h2[2048];
    __shared__ unsigned int wpre[16];
    __shared__ unsigned int s_b1, s_before;
    __shared__ int ctr, ttc;
    int c = min(tcnt[nlid], TCAP);
    unsigned int cnt_lt = thr[nlid * 2 + 1];
    int need = d_KL[l] - (int)cnt_lt;
    int tid = threadIdx.x, w = tid >> 6, lane = tid & 63;
    if (tid == 0) { ctr = 0; ttc = 0; }
    h2[tid] = 0; h2[tid + 1024] = 0;
    for (int i = tid; i < c; i += 1024) kk[i] = tiebuf[(size_t)nlid * TCAP + i];
    __syncthreads();
    for (int i = tid; i < c; i += 1024)
        atomicAdd(&h2[(unsigned int)((kk[i] >> 27) & 0x7ffull)], 1u);
    __syncthreads();
    unsigned int v0 = h2[2 * tid], v1 = h2[2 * tid + 1];
    unsigned int s = v0 + v1, ps = s;
    #pragma unroll
    for (int d = 1; d < 64; d <<= 1) {
        unsigned int t2 = (unsigned int)__shfl_up((int)ps, d, 64);
        if (lane >= d) ps += t2;
    }
    if (lane == 63) wpre[w] = ps;
    __syncthreads();
    unsigned int base = 0;
    #pragma unroll
    for (int ww = 0; ww < 16; ++ww) if (ww < w) base += wpre[ww];
    unsigned int incl = base + ps;
    unsigned int target = (unsigned int)need;
    unsigned int exc0 = incl - s, inc0 = incl - v1;
    unsigned int exc1 = inc0,    inc1 = incl;
    if (exc0 < target && target <= inc0) { s_b1 = 2 * tid;     s_before = exc0; }
    if (exc1 < target && target <= inc1) { s_b1 = 2 * tid + 1; s_before = exc1; }
    __syncthreads();
    unsigned int b1 = s_b1;
    int before = (int)s_before;
    int cbase = n * NSEL + d_LOFF[l];
    int koff = d_KOFF[l];
    for (int i = tid; i < c; i += 1024) {
        unsigned long long ki = kk[i];
        unsigned int sb = (unsigned int)((ki >> 27) & 0x7ffull);
        if (sb < b1) {                       // sure winner, arbitrary slot
            int slot = atomicAdd(&ctr, 1);
            int p = (int)(ki & 0x1ffffull);
            cg[cbase + (int)cnt_lt + slot] = koff + p;
            cl[cbase + (int)cnt_lt + slot] = logit_from_dkey((unsigned int)(ki >> 17));
        } else if (sb == b1) {
            int j = atomicAdd(&ttc, 1);
            if (j < TTCAP) tt[j] = ki;
        }
    }
    __syncthreads();
    int c2 = min(ttc, TTCAP);
    int need2 = need - before;
    for (int i = tid; i < c2; i += 1024) {
        unsigned long long ki = tt[i];
        int rank = 0;
        for (int j = 0; j < c2; ++j) rank += (tt[j] < ki) ? 1 : 0;
        if (rank < need2) {                  // ranks unique (p unique)
            int p = (int)(ki & 0x1ffffull);
            cg[cbase + (int)cnt_lt + before + rank] = koff + p;
            cl[cbase + (int)cnt_lt + before + rank] = logit_from_dkey((unsigned int)(ki >> 17));
        }
    }
}

// ---- decode + per-(image,level) bitonic sort, fused (same-block dep) -------
__global__ __launch_bounds__(512) void k_sortL(Ptrs P, const int* cg, const float* cl,
                                               unsigned long long* skey,
                                               float4* sboxL, float4* cboxL, float* slogL,
                                               int* ccnt) {
#pragma clang fp contract(off)
    __shared__ unsigned long long s[1024];
    __shared__ float4 lbox[1024];
    __shared__ float4 lbn[1024];
    __shared__ float llog[1024];
    int nl = blockIdx.x, tid = threadIdx.x;
    int n = nl / NLV, l = nl % NLV;
    #pragma unroll
    for (int half = 0; half < 2; ++half) {
        int j = tid + half * 512;
        if (j >= d_KL[l]) {                  // padding slot
            s[j] = ((unsigned long long)0xFFFFFFFFu << 27) | (unsigned long long)j;
            lbox[j] = make_float4(0.f, 0.f, 0.f, 0.f);
            lbn[j]  = make_float4(0.f, 0.f, 0.f, 0.f);
            llog[j] = 0.f;
            continue;
        }
        int src = n * NSEL + d_LOFF[l] + j;
        int gidx = cg[src];
        float lg = cl[src];
        int p = gidx - d_KOFF[l];
        int Wl = d_W[l];
        int HW = Wl * Wl;
        int a = p % 3, hw = p / 3;
        int h = hw / Wl, ww2 = hw - h * Wl;
        const float* dl = P.del[l];
        size_t base = (size_t)(n * 12 + a * 4) * HW + (size_t)h * Wl + ww2;
        float dx = dl[base], dy = dl[base + HW];
        float dw = dl[base + 2 * (size_t)HW], dh = dl[base + 3 * (size_t)HW];
        const float* an = P.anch + 4 * (size_t)gidx;
        float ax1 = an[0], ay1 = an[1], ax2 = an[2], ay2 = an[3];
        float wa = ax2 - ax1, ha = ay2 - ay1;
        float cxa = ax1 + 0.5f * wa, cya = ay1 + 0.5f * ha;
        const float CLIPC = (float)4.135166556742356;
        dw = fminf(dw, CLIPC); dh = fminf(dh, CLIPC);
        float cx = dx * wa + cxa;
        float cy = dy * ha + cya;
        float ww = expf(dw) * wa;
        float hh = expf(dh) * ha;
        float x1 = cx - 0.5f * ww, y1 = cy - 0.5f * hh;
        float x2 = cx + 0.5f * ww, y2 = cy + 0.5f * hh;
        x1 = fminf(fmaxf(x1, 0.0f), 800.0f);
        y1 = fminf(fmaxf(y1, 0.0f), 800.0f);
        x2 = fminf(fmaxf(x2, 0.0f), 800.0f);
        y2 = fminf(fmaxf(y2, 0.0f), 800.0f);
        bool valid = (x2 - x1 >= 1e-3f) && (y2 - y1 >= 1e-3f);
        float off = (float)l * 801.0f;
        lbox[j] = make_float4(x1, y1, x2, y2);
        lbn[j]  = make_float4(x1 + off, y1 + off, x2 + off, y2 + off);
        llog[j] = lg;
        unsigned int sk = valid ? dkey_of(lg) : 0xffffffffu;
        s[j] = ((unsigned long long)sk << 27) |
               ((unsigned long long)(unsigned int)p << 10) | (unsigned long long)j;
    }
    __syncthreads();
    for (int k = 2; k <= 1024; k <<= 1) {
        for (int j = k >> 1; j > 0; j >>= 1) {
            int i = ((tid & ~(j - 1)) << 1) | (tid & (j - 1));
            int ix = i | j;
            bool up = ((i & k) == 0);
            unsigned long long A = s[i], B = s[ix];
            if ((A > B) == up) { s[i] = B; s[ix] = A; }
            __syncthreads();
        }
    }
    for (int e = tid; e < 1024; e += 512) {
        unsigned long long key = s[e];
        int j = (int)(key & 0x3ffull);
        skey[nl * 1024 + e] = key;
        sboxL[nl * 1024 + e] = lbox[j];
        cboxL[nl * 1024 + e] = lbn[j];
        slogL[nl * 1024 + e] = llog[j];
        bool v = (key >> 27) != 0xFFFFFFFFull;
        bool vn = (e < 1023) ? ((s[e + 1] >> 27) != 0xFFFFFFFFull) : false;
        if (e == 0 && !v) ccnt[nl] = 0;
        if (v && (e == 1023 || !vn)) ccnt[nl] = e + 1;
    }
}

// --------------- pairwise suppression mask, whole-chip parallel -------------
// MT TRANSPOSED: MT[(nl*16 + colword)*1024 + row]. Upper triangle only.
__global__ __launch_bounds__(256) void k_mask(const float4* cboxL, const int* ccnt,
                                              unsigned long long* MT) {
#pragma clang fp contract(off)
    int n = blockIdx.z, l = blockIdx.y;
    int ci = blockIdx.x >> 4, cj = blockIdx.x & 15;
    int nl = n * NLV + l;
    int cnt = ccnt[nl];
    int nw = (cnt + 63) / 64;
    if (cj < ci || cj >= nw) return;
    __shared__ float4 bi[64], bj[64];
    int tid = threadIdx.x;
    if (tid < 64) bj[tid] = cboxL[nl * 1024 + cj * 64 + tid];
    else if (tid < 128) bi[tid - 64] = cboxL[nl * 1024 + ci * 64 + (tid - 64)];
    __syncthreads();
    int w = tid >> 6, lane = tid & 63;
    float4 B = bj[lane];
    float a2 = (B.z - B.x) * (B.w - B.y);
    unsigned long long* outp = MT + ((size_t)nl * 16 + cj) * 1024 + ci * 64;
    #pragma unroll
    for (int t = 0; t < 16; ++t) {
        int i = w * 16 + t;
        float4 A = bi[i];
        float a1 = (A.z - A.x) * (A.w - A.y);
        float ltx = fmaxf(A.x, B.x), lty = fmaxf(A.y, B.y);
        float rbx = fminf(A.z, B.z), rby = fminf(A.w, B.w);
        float wx = fmaxf(rbx - ltx, 0.f), wy = fmaxf(rby - lty, 0.f);
        float inter = wx * wy;
        float iou = inter / ((a1 + a2) - inter);   // NaN (0/0) -> false, like jnp
        unsigned long long word = __ballot(iou > 0.7f);
        if (lane == 0) outp[i] = word;
    }
}

// --------------- batched greedy NMS scan: fixpoint rounds -------------------
__global__ __launch_bounds__(1024) void k_scan(const unsigned long long* MT,
                                               const int* ccnt,
                                               unsigned long long* keepL) {
    int l = blockIdx.x, n = blockIdx.y;
    int nl = n * NLV + l;
    int tid = threadIdx.x, w = tid >> 6, lane = tid & 63;
    __shared__ unsigned long long pendS[16];
    __shared__ unsigned long long defS[16];
    int cnt = ccnt[nl];
    int nw = (cnt + 63) / 64;

    const unsigned long long* base = MT + ((size_t)nl * 16 + w) * 1024;
    unsigned long long Dmask = 0;
    if (w < nw)
        Dmask = base[(size_t)w * 64 + lane] & ~((2ull << lane) - 1ull);
    unsigned long long rows[15];
    #pragma unroll
    for (int cc = 0; cc < 15; ++cc)
        rows[cc] = (cc < w && w < nw) ? base[(size_t)cc * 64 + lane] : 0ull;

    int nb = max(0, min(64, cnt - w * 64));
    unsigned long long pend_w = (nb == 64) ? ~0ull : ((nb > 0) ? ((1ull << nb) - 1ull) : 0ull);
    unsigned long long K_w = 0;
    if (lane == 0) pendS[w] = pend_w;
    __syncthreads();

    for (int round = 0; round < 1024; ++round) {
        unsigned long long any = 0;
        #pragma unroll
        for (int cc = 0; cc < 16; ++cc) any |= pendS[cc];
        if (!any) break;
        unsigned long long acc = ((pendS[w] >> lane) & 1ull) ? Dmask : 0ull;
        #pragma unroll
        for (int cc = 0; cc < 15; ++cc)
            if (cc < w) acc |= ((pendS[cc] >> lane) & 1ull) ? rows[cc] : 0ull;
        unsigned int vlo = (unsigned int)acc, vhi = (unsigned int)(acc >> 32);
        #pragma unroll
        for (int m = 1; m < 64; m <<= 1) {
            vlo |= (unsigned int)__shfl_xor((int)vlo, m, 64);
            vhi |= (unsigned int)__shfl_xor((int)vhi, m, 64);
        }
        unsigned long long sup = ((unsigned long long)vhi << 32) | (unsigned long long)vlo;
        unsigned long long def_w = pend_w & ~sup;
        K_w |= def_w;
        if (lane == 0) defS[w] = def_w;
        __syncthreads();
        unsigned long long acc2 = ((defS[w] >> lane) & 1ull) ? Dmask : 0ull;
        #pragma unroll
        for (int cc = 0; cc < 15; ++cc)
            if (cc < w) acc2 |= ((defS[cc] >> lane) & 1ull) ? rows[cc] : 0ull;
        unsigned int rlo = (unsigned int)acc2, rhi = (unsigned int)(acc2 >> 32);
        #pragma unroll
        for (int m = 1; m < 64; m <<= 1) {
            rlo |= (unsigned int)__shfl_xor((int)rlo, m, 64);
            rhi |= (unsigned int)__shfl_xor((int)rhi, m, 64);
        }
        unsigned long long rem = ((unsigned long long)rhi << 32) | (unsigned long long)rlo;
        pend_w &= ~def_w & ~rem;
        if (lane == 0) pendS[w] = pend_w;
        __syncthreads();
    }
    if (lane == 0) keepL[nl * 16 + w] = K_w;
}

// --------------- rank-merge: kept boxes -> global score order -> output -----
__global__ __launch_bounds__(1024) void k_rank(const unsigned long long* skey,
                                               const unsigned long long* keepL,
                                               const int* ccnt,
                                               const float4* sboxL, const float* slogL,
                                               float* out) {
    int n = blockIdx.x, tid = threadIdx.x;
    __shared__ unsigned long long KS[NLV][1024];
    __shared__ unsigned long long kd[NLV][16];
    __shared__ int kpre[NLV][17];
    __shared__ int lcnt[NLV];
    for (int i = tid; i < POSTN; i += 1024) {     // zero-init this image slice
        ((float4*)out)[n * POSTN + i] = make_float4(0.f, 0.f, 0.f, 0.f);
        out[NIMG * POSTN * 4 + n * POSTN + i] = 0.f;
    }
    for (int e = tid; e < NLV * 1024; e += 1024)
        ((unsigned long long*)KS)[e] = skey[(size_t)n * NLV * 1024 + e];
    if (tid < NLV * 16) ((unsigned long long*)kd)[tid] = keepL[n * NLV * 16 + tid];
    if (tid < NLV) lcnt[tid] = ccnt[n * NLV + tid];
    __syncthreads();
    if (tid < NLV) {
        int run = 0;
        for (int q = 0; q < 16; ++q) { kpre[tid][q] = run; run += (int)__popcll(kd[tid][q]); }
        kpre[tid][16] = run;
    }
    __syncthreads();
    for (int e = tid; e < NLV * 1024; e += 1024) {
        int l = e >> 10, i = e & 1023;
        if (i >= lcnt[l]) continue;
        int q = i >> 6, b = i & 63;
        if (!((kd[l][q] >> b) & 1ull)) continue;
        int rank = kpre[l][q] + (int)__popcll(kd[l][q] & ((1ull << b) - 1ull));
        unsigned int sk = (unsigned int)(KS[l][i] >> 27);
        for (int l2 = 0; l2 < NLV; ++l2) {
            if (l2 == l) continue;
            int c2 = lcnt[l2];
            unsigned long long bound = (l2 < l)
                ? (((unsigned long long)sk + 1ull) << 27)   // sk' <= sk
                : ((unsigned long long)sk << 27);           // sk' <  sk
            int lo = 0, hi = c2;
            while (lo < hi) {
                int mid = (lo + hi) >> 1;
                if (KS[l2][mid] < bound) lo = mid + 1; else hi = mid;
            }
            int mq = lo >> 6, mb = lo & 63;
            rank += kpre[l2][mq] + (mb ? (int)__popcll(kd[l2][mq] & ((1ull << mb) - 1ull)) : 0);
        }
        if (rank < POSTN) {
            ((float4*)out)[n * POSTN + rank] = sboxL[(size_t)(n * NLV + l) * 1024 + i];
            float lg = slogL[(size_t)(n * NLV + l) * 1024 + i];
            out[NIMG * POSTN * 4 + n * POSTN + rank] = 1.0f / (1.0f + expf(-lg));
        }
    }
}

extern "C" void kernel_launch(void* const* d_in, const int* in_sizes, int n_in,
                              void* d_out, int out_size, void* d_ws, size_t ws_size,
                              hipStream_t stream) {
    Ptrs P;
    bool interleaved = (in_sizes[1] == 4 * in_sizes[0]);
    for (int i = 0; i < NLV; ++i) {
        if (interleaved) {
            P.obj[i] = (const float*)d_in[2 * i];
            P.del[i] = (const float*)d_in[2 * i + 1];
        } else {
            P.obj[i] = (const float*)d_in[i];
            P.del[i] = (const float*)d_in[NLV + i];
        }
    }
    P.anch = (const float*)d_in[10];

    char* w = (char*)d_ws;
    size_t off = 0;
    auto alloc = [&](size_t bytes) {
        void* p = w + off;
        off = (off + bytes + 255) & ~(size_t)255;
        return p;
    };
    const size_t NLT = (size_t)NIMG * NLV * 1024;
    unsigned int* hcnt = (unsigned int*)alloc(256);   // 20 used, memset-zeroed
    unsigned int* hist = (unsigned int*)alloc((size_t)NIMG * NLV * NHB * 2048 * 4);
    int* scnt = (int*)alloc(256);
    int* tcnt = (int*)alloc(256);
    unsigned int* thr = (unsigned int*)alloc((size_t)NIMG * NLV * 2 * 4);
    unsigned long long* tiebuf = (unsigned long long*)alloc((size_t)NIMG * NLV * TCAP * 8);
    int* cg      = (int*)alloc((size_t)TSEL * 4);
    float* cl    = (float*)alloc((size_t)TSEL * 4);
    unsigned long long* skey = (unsigned long long*)alloc(NLT * 8);
    float4* sboxL = (float4*)alloc(NLT * 16);
    float4* cboxL = (float4*)alloc(NLT * 16);
    float* slogL  = (float*)alloc(NLT * 4);
    int* ccnt    = (int*)alloc((size_t)NIMG * NLV * 4);
    unsigned long long* keepL = (unsigned long long*)alloc((size_t)NIMG * NLV * 16 * 8);
    unsigned long long* MT = (unsigned long long*)alloc((size_t)NIMG * NLV * 16 * 1024 * 8);
    (void)ws_size; (void)n_in;

    (void)hipMemsetAsync(hcnt, 0, 256, stream);
    k_hist<<<dim3(NHB, NLV, NIMG), 1024, 0, stream>>>(P, hist, hcnt, thr, scnt, tcnt);
    k_pick<<<dim3(PBLK, NLV, NIMG), 256, 0, stream>>>(P, thr, scnt, tcnt, cg, cl, tiebuf);
    k_tie<<<NIMG * NLV, 1024, 0, stream>>>(thr, tcnt, tiebuf, cg, cl);
    k_sortL<<<NIMG * NLV, 512, 0, stream>>>(P, cg, cl, skey, sboxL, cboxL, slogL, ccnt);
    k_mask<<<dim3(256, NLV, NIMG), 256, 0, stream>>>(cboxL, ccnt, MT);
    k_scan<<<dim3(NLV, NIMG), 1024, 0, stream>>>(MT, ccnt, keepL);
    k_rank<<<NIMG, 1024, 0, stream>>>(skey, keepL, ccnt, sboxL, slogL, (float*)d_out);
}

// Round 18
// 169.468 us; speedup vs baseline: 1.5176x; 1.5176x over previous
//
#include <hip/hip_runtime.h>
#include <cstdint>
#include <cstddef>

#define NLV 5
#define NIMG 4
#define NSEL 4507          // 1000+1000+1000+1000+507 selected per image
#define TSEL (NIMG * NSEL)
#define POSTN 1000
#define TCAP 8192          // boundary-bin candidate cap
#define TTCAP 2048         // sub-boundary (tie-of-tie) cap
#define NHB 16             // sub-histograms per (image,level)
#define PBLK 64            // k_pick blocks per (image,level)
#define PCH 1875           // max chunk for k_pick (120000/64)

__device__ const int d_W[NLV]    = {200, 100, 50, 25, 13};
__device__ const int d_NL[NLV]   = {120000, 30000, 7500, 1875, 507};
__device__ const int d_KOFF[6]   = {0, 120000, 150000, 157500, 159375, 159882};
__device__ const int d_LOFF[6]   = {0, 1000, 2000, 3000, 4000, 4507};
__device__ const int d_KL[NLV]   = {1000, 1000, 1000, 1000, 507};

struct Ptrs {
    const float* obj[NLV];
    const float* del[NLV];
    const float* anch;
};

// order-preserving map: dk ascending <=> float descending
__device__ inline unsigned int dkey_of(float f) {
    unsigned int u = __float_as_uint(f);
    unsigned int mk = (u & 0x80000000u) ? ~u : (u | 0x80000000u);
    return ~mk;
}
__device__ inline float logit_from_dkey(unsigned int dk) {
    unsigned int mk = ~dk;
    unsigned int u = (mk & 0x80000000u) ? (mk & 0x7fffffffu) : ~mk;
    return __uint_as_float(u);
}

// ---------------- top-k stage 1: LDS-private histograms, plain stores -------
// 256 threads/block, scalar chunked loads: measured-best config (round 13).
// 1024-thr + float4 variant REGRESSED (106us vs ~40): same-address LDS
// atomics serialize; more co-issuing waves only deepen the queue.
__global__ __launch_bounds__(256) void k_hist(Ptrs P, unsigned int* hist) {
    int l = blockIdx.y, n = blockIdx.z;
    int nl_sz = d_NL[l];
    if (d_KL[l] >= nl_sz) return;            // level 4: all selected
    int nlid = n * NLV + l;
    __shared__ unsigned int h[2048];
    for (int i = threadIdx.x; i < 2048; i += 256) h[i] = 0;
    __syncthreads();
    const float* ob = P.obj[l] + (size_t)n * nl_sz;
    int chunk = (nl_sz + NHB - 1) / NHB;
    int beg = blockIdx.x * chunk;
    int end = min(beg + chunk, nl_sz);
    for (int t = beg + (int)threadIdx.x; t < end; t += 256)
        atomicAdd(&h[dkey_of(ob[t]) >> 21], 1u);   // LDS atomic
    __syncthreads();
    unsigned int* out = hist + ((size_t)nlid * NHB + blockIdx.x) * 2048;
    for (int i = threadIdx.x; i < 2048; i += 256) out[i] = h[i];
}

// ---------------- top-k stage 2: reduce sub-hists, boundary bin -------------
// Separate dispatch (fusing via last-block __threadfence cost ~11us — r15).
__global__ __launch_bounds__(1024) void k_thresh(const unsigned int* hist,
                                                 unsigned int* thr,
                                                 int* scnt, int* tcnt) {
    int nlid = blockIdx.x;
    int l = nlid % NLV;
    if (threadIdx.x == 0) { scnt[nlid] = 0; tcnt[nlid] = 0; }
    if (d_KL[l] >= d_NL[l]) return;
    int tid = threadIdx.x, w = tid >> 6, lane = tid & 63;
    __shared__ unsigned int wpre[16];
    const unsigned int* hb = hist + (size_t)nlid * NHB * 2048;
    unsigned int v0 = 0, v1 = 0;
    #pragma unroll
    for (int sh = 0; sh < NHB; ++sh) {
        v0 += hb[sh * 2048 + 2 * tid];
        v1 += hb[sh * 2048 + 2 * tid + 1];
    }
    unsigned int s = v0 + v1;
    unsigned int ps = s;
    #pragma unroll
    for (int d = 1; d < 64; d <<= 1) {
        unsigned int t2 = (unsigned int)__shfl_up((int)ps, d, 64);
        if (lane >= d) ps += t2;
    }
    if (lane == 63) wpre[w] = ps;
    __syncthreads();
    unsigned int base = 0;
    #pragma unroll
    for (int ww = 0; ww < 16; ++ww) if (ww < w) base += wpre[ww];
    unsigned int incl = base + ps;           // inclusive prefix over PAIRS
    unsigned int target = (unsigned int)d_KL[l];
    unsigned int exc0 = incl - s, inc0 = incl - v1;
    unsigned int exc1 = inc0,    inc1 = incl;
    if (exc0 < target && target <= inc0) { thr[nlid * 2] = 2 * tid;     thr[nlid * 2 + 1] = exc0; }
    if (exc1 < target && target <= inc1) { thr[nlid * 2] = 2 * tid + 1; thr[nlid * 2 + 1] = exc1; }
}

// ---------------- top-k stage 3: pick winners, block-aggregated atomics -----
// LEAN kernel (30KB LDS, ~5 blocks/CU). Fusing tie here ballooned LDS to
// 54.8KB -> 2 blocks/CU -> 92us (round-15 lesson).
__global__ __launch_bounds__(256) void k_pick(Ptrs P, const unsigned int* thr,
                                              int* scnt, int* tcnt,
                                              int* cg, float* cl,
                                              unsigned long long* tiebuf) {
    int l = blockIdx.y, n = blockIdx.z;
    int nl_sz = d_NL[l], kl = d_KL[l];
    int nlid = n * NLV + l;
    const float* ob = P.obj[l] + (size_t)n * nl_sz;
    int cbase = n * NSEL + d_LOFF[l];
    int koff = d_KOFF[l];
    int Wl = d_W[l], HW = Wl * Wl;
    int chunk = (nl_sz + PBLK - 1) / PBLK;
    int beg = blockIdx.x * chunk;
    int end = min(beg + chunk, nl_sz);
    int tid = threadIdx.x;

    if (kl >= nl_sz) {                       // level 4: deterministic slots
        for (int t = beg + tid; t < end; t += 256) {
            int a = t / HW, rem = t - a * HW;
            int p = rem * 3 + a;
            cg[cbase + p] = koff + p;
            cl[cbase + p] = ob[t];
        }
        return;
    }
    __shared__ int sp[PCH];
    __shared__ float sl[PCH];
    __shared__ unsigned long long tb[PCH];
    __shared__ int nsel, ntie, sbase, tbase;
    if (tid == 0) { nsel = 0; ntie = 0; }
    __syncthreads();

    unsigned int b0 = thr[nlid * 2];
    for (int t = beg + tid; t < end; t += 256) {
        float lg = ob[t];
        unsigned int dk = dkey_of(lg);
        unsigned int bin = dk >> 21;
        if (bin < b0) {
            int pos = atomicAdd(&nsel, 1);   // LDS atomic
            int a = t / HW, rem = t - a * HW;
            sp[pos] = rem * 3 + a;
            sl[pos] = lg;
        } else if (bin == b0) {
            int pos = atomicAdd(&ntie, 1);   // LDS atomic
            int a = t / HW, rem = t - a * HW;
            tb[pos] = ((unsigned long long)dk << 17) |
                      (unsigned long long)(unsigned int)(rem * 3 + a);
        }
    }
    __syncthreads();
    if (tid == 0) {
        sbase = atomicAdd(&scnt[nlid], nsel);  // 1 global atomic / block
        tbase = atomicAdd(&tcnt[nlid], ntie);
    }
    __syncthreads();
    int ns = nsel, nt = ntie, sb = sbase, tbs = tbase;
    for (int i = tid; i < ns; i += 256) {
        cg[cbase + sb + i] = koff + sp[i];
        cl[cbase + sb + i] = sl[i];
    }
    for (int i = tid; i < nt; i += 256) {
        int slot = tbs + i;
        if (slot < TCAP) tiebuf[(size_t)nlid * TCAP + slot] = tb[i];
    }
}

// ---------------- top-k stage 4: boundary candidates, radix-refined ---------
__global__ __launch_bounds__(1024) void k_tie(const unsigned int* thr, const int* tcnt,
                                              const unsigned long long* tiebuf,
                                              int* cg, float* cl) {
    int nlid = blockIdx.x;
    int n = nlid / NLV, l = nlid % NLV;
    if (d_KL[l] >= d_NL[l]) return;
    __shared__ unsigned long long kk[TCAP];
    __shared__ unsigned long long tt[TTCAP];
    __shared__ unsigned int h2[2048];
    __shared__ unsigned int wpre[16];
    __shared__ unsigned int s_b1, s_before;
    __shared__ int ctr, ttc;
    int c = min(tcnt[nlid], TCAP);
    unsigned int cnt_lt = thr[nlid * 2 + 1];
    int need = d_KL[l] - (int)cnt_lt;
    int tid = threadIdx.x, w = tid >> 6, lane = tid & 63;
    if (tid == 0) { ctr = 0; ttc = 0; }
    h2[tid] = 0; h2[tid + 1024] = 0;
    for (int i = tid; i < c; i += 1024) kk[i] = tiebuf[(size_t)nlid * TCAP + i];
    __syncthreads();
    for (int i = tid; i < c; i += 1024)
        atomicAdd(&h2[(unsigned int)((kk[i] >> 27) & 0x7ffull)], 1u);
    __syncthreads();
    unsigned int v0 = h2[2 * tid], v1 = h2[2 * tid + 1];
    unsigned int s = v0 + v1, ps = s;
    #pragma unroll
    for (int d = 1; d < 64; d <<= 1) {
        unsigned int t2 = (unsigned int)__shfl_up((int)ps, d, 64);
        if (lane >= d) ps += t2;
    }
    if (lane == 63) wpre[w] = ps;
    __syncthreads();
    unsigned int base = 0;
    #pragma unroll
    for (int ww = 0; ww < 16; ++ww) if (ww < w) base += wpre[ww];
    unsigned int incl = base + ps;
    unsigned int target = (unsigned int)need;
    unsigned int exc0 = incl - s, inc0 = incl - v1;
    unsigned int exc1 = inc0,    inc1 = incl;
    if (exc0 < target && target <= inc0) { s_b1 = 2 * tid;     s_before = exc0; }
    if (exc1 < target && target <= inc1) { s_b1 = 2 * tid + 1; s_before = exc1; }
    __syncthreads();
    unsigned int b1 = s_b1;
    int before = (int)s_before;
    int cbase = n * NSEL + d_LOFF[l];
    int koff = d_KOFF[l];
    for (int i = tid; i < c; i += 1024) {
        unsigned long long ki = kk[i];
        unsigned int sb = (unsigned int)((ki >> 27) & 0x7ffull);
        if (sb < b1) {                       // sure winner, arbitrary slot
            int slot = atomicAdd(&ctr, 1);
            int p = (int)(ki & 0x1ffffull);
            cg[cbase + (int)cnt_lt + slot] = koff + p;
            cl[cbase + (int)cnt_lt + slot] = logit_from_dkey((unsigned int)(ki >> 17));
        } else if (sb == b1) {
            int j = atomicAdd(&ttc, 1);
            if (j < TTCAP) tt[j] = ki;
        }
    }
    __syncthreads();
    int c2 = min(ttc, TTCAP);
    int need2 = need - before;
    for (int i = tid; i < c2; i += 1024) {
        unsigned long long ki = tt[i];
        int rank = 0;
        for (int j = 0; j < c2; ++j) rank += (tt[j] < ki) ? 1 : 0;
        if (rank < need2) {                  // ranks unique (p unique)
            int p = (int)(ki & 0x1ffffull);
            cg[cbase + (int)cnt_lt + before + rank] = koff + p;
            cl[cbase + (int)cnt_lt + before + rank] = logit_from_dkey((unsigned int)(ki >> 17));
        }
    }
}

// --------------- decode, clip, validity; per-level key ----------------------
__global__ __launch_bounds__(256) void k_build(Ptrs P, const int* cg, const float* cl,
                                               unsigned long long* pkey,
                                               float4* pbox, float4* pbn, float* plog) {
#pragma clang fp contract(off)
    int t = blockIdx.x * blockDim.x + threadIdx.x;
    if (t >= NIMG * NLV * 1024) return;
    int nl = t >> 10, j = t & 1023;
    int n = nl / NLV, l = nl % NLV;
    if (j >= d_KL[l]) {                      // padding slot
        pkey[t] = ((unsigned long long)0xFFFFFFFFu << 27) | (unsigned long long)j;
        pbox[t] = make_float4(0.f, 0.f, 0.f, 0.f);
        pbn[t]  = make_float4(0.f, 0.f, 0.f, 0.f);
        plog[t] = 0.f;
        return;
    }
    int s = n * NSEL + d_LOFF[l] + j;
    int gidx = cg[s];
    float lg = cl[s];
    int p = gidx - d_KOFF[l];
    int Wl = d_W[l];
    int HW = Wl * Wl;
    int a = p % 3, hw = p / 3;
    int h = hw / Wl, w = hw - h * Wl;
    const float* dl = P.del[l];
    size_t base = (size_t)(n * 12 + a * 4) * HW + (size_t)h * Wl + w;
    float dx = dl[base], dy = dl[base + HW];
    float dw = dl[base + 2 * (size_t)HW], dh = dl[base + 3 * (size_t)HW];
    const float* an = P.anch + 4 * (size_t)gidx;
    float ax1 = an[0], ay1 = an[1], ax2 = an[2], ay2 = an[3];
    float wa = ax2 - ax1, ha = ay2 - ay1;
    float cxa = ax1 + 0.5f * wa, cya = ay1 + 0.5f * ha;
    const float CLIPC = (float)4.135166556742356;
    dw = fminf(dw, CLIPC); dh = fminf(dh, CLIPC);
    float cx = dx * wa + cxa;
    float cy = dy * ha + cya;
    float ww = expf(dw) * wa;
    float hh = expf(dh) * ha;
    float x1 = cx - 0.5f * ww, y1 = cy - 0.5f * hh;
    float x2 = cx + 0.5f * ww, y2 = cy + 0.5f * hh;
    x1 = fminf(fmaxf(x1, 0.0f), 800.0f);
    y1 = fminf(fmaxf(y1, 0.0f), 800.0f);
    x2 = fminf(fmaxf(x2, 0.0f), 800.0f);
    y2 = fminf(fmaxf(y2, 0.0f), 800.0f);
    bool valid = (x2 - x1 >= 1e-3f) && (y2 - y1 >= 1e-3f);
    float off = (float)l * 801.0f;
    pbox[t] = make_float4(x1, y1, x2, y2);
    pbn[t]  = make_float4(x1 + off, y1 + off, x2 + off, y2 + off);
    plog[t] = lg;
    unsigned int sk = valid ? dkey_of(lg) : 0xffffffffu;
    pkey[t] = ((unsigned long long)sk << 27) |
              ((unsigned long long)(unsigned int)p << 10) | (unsigned long long)j;
}

// --------------- per-(image,level) bitonic sort of 1024 keys ----------------
__global__ __launch_bounds__(512) void k_sortL(const unsigned long long* pkey,
                                               const float4* pbox, const float4* pbn,
                                               const float* plog,
                                               unsigned long long* skey,
                                               float4* sboxL, float4* cboxL, float* slogL,
                                               int* ccnt) {
    __shared__ unsigned long long s[1024];
    int nl = blockIdx.x, tid = threadIdx.x;
    s[tid] = pkey[nl * 1024 + tid];
    s[tid + 512] = pkey[nl * 1024 + tid + 512];
    __syncthreads();
    for (int k = 2; k <= 1024; k <<= 1) {
        for (int j = k >> 1; j > 0; j >>= 1) {
            int i = ((tid & ~(j - 1)) << 1) | (tid & (j - 1));
            int ix = i | j;
            bool up = ((i & k) == 0);
            unsigned long long A = s[i], B = s[ix];
            if ((A > B) == up) { s[i] = B; s[ix] = A; }
            __syncthreads();
        }
    }
    for (int e = tid; e < 1024; e += 512) {
        unsigned long long key = s[e];
        int j = (int)(key & 0x3ffull);
        int src = nl * 1024 + j;
        skey[nl * 1024 + e] = key;
        sboxL[nl * 1024 + e] = pbox[src];
        cboxL[nl * 1024 + e] = pbn[src];
        slogL[nl * 1024 + e] = plog[src];
        bool v = (key >> 27) != 0xFFFFFFFFull;
        bool vn = (e < 1023) ? ((s[e + 1] >> 27) != 0xFFFFFFFFull) : false;
        if (e == 0 && !v) ccnt[nl] = 0;
        if (v && (e == 1023 || !vn)) ccnt[nl] = e + 1;
    }
}

// --------------- pairwise suppression mask, whole-chip parallel -------------
// MT TRANSPOSED: MT[(nl*16 + colword)*1024 + row]. Upper triangle only.
__global__ __launch_bounds__(256) void k_mask(const float4* cboxL, const int* ccnt,
                                              unsigned long long* MT) {
#pragma clang fp contract(off)
    int n = blockIdx.z, l = blockIdx.y;
    int ci = blockIdx.x >> 4, cj = blockIdx.x & 15;
    int nl = n * NLV + l;
    int cnt = ccnt[nl];
    int nw = (cnt + 63) / 64;
    if (cj < ci || cj >= nw) return;
    __shared__ float4 bi[64], bj[64];
    int tid = threadIdx.x;
    if (tid < 64) bj[tid] = cboxL[nl * 1024 + cj * 64 + tid];
    else if (tid < 128) bi[tid - 64] = cboxL[nl * 1024 + ci * 64 + (tid - 64)];
    __syncthreads();
    int w = tid >> 6, lane = tid & 63;
    float4 B = bj[lane];
    float a2 = (B.z - B.x) * (B.w - B.y);
    unsigned long long* outp = MT + ((size_t)nl * 16 + cj) * 1024 + ci * 64;
    #pragma unroll
    for (int t = 0; t < 16; ++t) {
        int i = w * 16 + t;
        float4 A = bi[i];
        float a1 = (A.z - A.x) * (A.w - A.y);
        float ltx = fmaxf(A.x, B.x), lty = fmaxf(A.y, B.y);
        float rbx = fminf(A.z, B.z), rby = fminf(A.w, B.w);
        float wx = fmaxf(rbx - ltx, 0.f), wy = fmaxf(rby - lty, 0.f);
        float inter = wx * wy;
        float iou = inter / ((a1 + a2) - inter);   // NaN (0/0) -> false, like jnp
        unsigned long long word = __ballot(iou > 0.7f);
        if (lane == 0) outp[i] = word;
    }
}

// --------------- batched greedy NMS scan: fixpoint rounds, no serial chain --
// Equivalence to sequential greedy: a PENDING box not suppressed by any
// EARLIER PENDING box is definitely kept; boxes suppressed by definite boxes
// are definitely removed; recurse. >=1 box resolved/round, typical ~2-3.
__global__ __launch_bounds__(1024) void k_scan(const unsigned long long* MT,
                                               const int* ccnt,
                                               unsigned long long* keepL) {
    int l = blockIdx.x, n = blockIdx.y;
    int nl = n * NLV + l;
    int tid = threadIdx.x, w = tid >> 6, lane = tid & 63;
    __shared__ unsigned long long pendS[16];
    __shared__ unsigned long long defS[16];
    int cnt = ccnt[nl];
    int nw = (cnt + 63) / 64;

    const unsigned long long* base = MT + ((size_t)nl * 16 + w) * 1024;
    unsigned long long Dmask = 0;
    if (w < nw)
        Dmask = base[(size_t)w * 64 + lane] & ~((2ull << lane) - 1ull);
    unsigned long long rows[15];
    #pragma unroll
    for (int cc = 0; cc < 15; ++cc)
        rows[cc] = (cc < w && w < nw) ? base[(size_t)cc * 64 + lane] : 0ull;

    int nb = max(0, min(64, cnt - w * 64));
    unsigned long long pend_w = (nb == 64) ? ~0ull : ((nb > 0) ? ((1ull << nb) - 1ull) : 0ull);
    unsigned long long K_w = 0;
    if (lane == 0) pendS[w] = pend_w;
    __syncthreads();

    for (int round = 0; round < 1024; ++round) {
        unsigned long long any = 0;
        #pragma unroll
        for (int cc = 0; cc < 16; ++cc) any |= pendS[cc];
        if (!any) break;
        unsigned long long acc = ((pendS[w] >> lane) & 1ull) ? Dmask : 0ull;
        #pragma unroll
        for (int cc = 0; cc < 15; ++cc)
            if (cc < w) acc |= ((pendS[cc] >> lane) & 1ull) ? rows[cc] : 0ull;
        unsigned int vlo = (unsigned int)acc, vhi = (unsigned int)(acc >> 32);
        #pragma unroll
        for (int m = 1; m < 64; m <<= 1) {
            vlo |= (unsigned int)__shfl_xor((int)vlo, m, 64);
            vhi |= (unsigned int)__shfl_xor((int)vhi, m, 64);
        }
        unsigned long long sup = ((unsigned long long)vhi << 32) | (unsigned long long)vlo;
        unsigned long long def_w = pend_w & ~sup;
        K_w |= def_w;
        if (lane == 0) defS[w] = def_w;
        __syncthreads();
        unsigned long long acc2 = ((defS[w] >> lane) & 1ull) ? Dmask : 0ull;
        #pragma unroll
        for (int cc = 0; cc < 15; ++cc)
            if (cc < w) acc2 |= ((defS[cc] >> lane) & 1ull) ? rows[cc] : 0ull;
        unsigned int rlo = (unsigned int)acc2, rhi = (unsigned int)(acc2 >> 32);
        #pragma unroll
        for (int m = 1; m < 64; m <<= 1) {
            rlo |= (unsigned int)__shfl_xor((int)rlo, m, 64);
            rhi |= (unsigned int)__shfl_xor((int)rhi, m, 64);
        }
        unsigned long long rem = ((unsigned long long)rhi << 32) | (unsigned long long)rlo;
        pend_w &= ~def_w & ~rem;
        if (lane == 0) pendS[w] = pend_w;
        __syncthreads();
    }
    if (lane == 0) keepL[nl * 16 + w] = K_w;
}

// --------------- rank-merge: kept boxes -> global score order -> output -----
// For SCORE TIES across levels the reference tiebreak is concat position =
// LEVEL asc (gidx ranges are level-disjoint) — bounds compare sk only:
// l2<l counts sk'<=sk, l2>l counts sk'<sk.
__global__ __launch_bounds__(1024) void k_rank(const unsigned long long* skey,
                                               const unsigned long long* keepL,
                                               const int* ccnt,
                                               const float4* sboxL, const float* slogL,
                                               float* out) {
    int n = blockIdx.x, tid = threadIdx.x;
    __shared__ unsigned long long KS[NLV][1024];
    __shared__ unsigned long long kd[NLV][16];
    __shared__ int kpre[NLV][17];
    __shared__ int lcnt[NLV];
    for (int i = tid; i < POSTN; i += 1024) {     // zero-init this image slice
        ((float4*)out)[n * POSTN + i] = make_float4(0.f, 0.f, 0.f, 0.f);
        out[NIMG * POSTN * 4 + n * POSTN + i] = 0.f;
    }
    for (int e = tid; e < NLV * 1024; e += 1024)
        ((unsigned long long*)KS)[e] = skey[(size_t)n * NLV * 1024 + e];
    if (tid < NLV * 16) ((unsigned long long*)kd)[tid] = keepL[n * NLV * 16 + tid];
    if (tid < NLV) lcnt[tid] = ccnt[n * NLV + tid];
    __syncthreads();
    if (tid < NLV) {
        int run = 0;
        for (int q = 0; q < 16; ++q) { kpre[tid][q] = run; run += (int)__popcll(kd[tid][q]); }
        kpre[tid][16] = run;
    }
    __syncthreads();
    for (int e = tid; e < NLV * 1024; e += 1024) {
        int l = e >> 10, i = e & 1023;
        if (i >= lcnt[l]) continue;
        int q = i >> 6, b = i & 63;
        if (!((kd[l][q] >> b) & 1ull)) continue;
        int rank = kpre[l][q] + (int)__popcll(kd[l][q] & ((1ull << b) - 1ull));
        unsigned int sk = (unsigned int)(KS[l][i] >> 27);
        for (int l2 = 0; l2 < NLV; ++l2) {
            if (l2 == l) continue;
            int c2 = lcnt[l2];
            unsigned long long bound = (l2 < l)
                ? (((unsigned long long)sk + 1ull) << 27)   // sk' <= sk
                : ((unsigned long long)sk << 27);           // sk' <  sk
            int lo = 0, hi = c2;
            while (lo < hi) {
                int mid = (lo + hi) >> 1;
                if (KS[l2][mid] < bound) lo = mid + 1; else hi = mid;
            }
            int mq = lo >> 6, mb = lo & 63;
            rank += kpre[l2][mq] + (mb ? (int)__popcll(kd[l2][mq] & ((1ull << mb) - 1ull)) : 0);
        }
        if (rank < POSTN) {
            ((float4*)out)[n * POSTN + rank] = sboxL[(size_t)(n * NLV + l) * 1024 + i];
            float lg = slogL[(size_t)(n * NLV + l) * 1024 + i];
            out[NIMG * POSTN * 4 + n * POSTN + rank] = 1.0f / (1.0f + expf(-lg));
        }
    }
}

extern "C" void kernel_launch(void* const* d_in, const int* in_sizes, int n_in,
                              void* d_out, int out_size, void* d_ws, size_t ws_size,
                              hipStream_t stream) {
    Ptrs P;
    bool interleaved = (in_sizes[1] == 4 * in_sizes[0]);
    for (int i = 0; i < NLV; ++i) {
        if (interleaved) {
            P.obj[i] = (const float*)d_in[2 * i];
            P.del[i] = (const float*)d_in[2 * i + 1];
        } else {
            P.obj[i] = (const float*)d_in[i];
            P.del[i] = (const float*)d_in[NLV + i];
        }
    }
    P.anch = (const float*)d_in[10];

    char* w = (char*)d_ws;
    size_t off = 0;
    auto alloc = [&](size_t bytes) {
        void* p = w + off;
        off = (off + bytes + 255) & ~(size_t)255;
        return p;
    };
    const size_t NLT = (size_t)NIMG * NLV * 1024;
    unsigned int* hist = (unsigned int*)alloc((size_t)NIMG * NLV * NHB * 2048 * 4);
    int* scnt = (int*)alloc(256);
    int* tcnt = (int*)alloc(256);
    unsigned int* thr = (unsigned int*)alloc((size_t)NIMG * NLV * 2 * 4);
    unsigned long long* tiebuf = (unsigned long long*)alloc((size_t)NIMG * NLV * TCAP * 8);
    int* cg      = (int*)alloc((size_t)TSEL * 4);
    float* cl    = (float*)alloc((size_t)TSEL * 4);
    unsigned long long* pkey = (unsigned long long*)alloc(NLT * 8);
    float4* pbox = (float4*)alloc(NLT * 16);
    float4* pbn  = (float4*)alloc(NLT * 16);
    float* plog  = (float*)alloc(NLT * 4);
    unsigned long long* skey = (unsigned long long*)alloc(NLT * 8);
    float4* sboxL = (float4*)alloc(NLT * 16);
    float4* cboxL = (float4*)alloc(NLT * 16);
    float* slogL  = (float*)alloc(NLT * 4);
    int* ccnt    = (int*)alloc((size_t)NIMG * NLV * 4);
    unsigned long long* keepL = (unsigned long long*)alloc((size_t)NIMG * NLV * 16 * 8);
    unsigned long long* MT = (unsigned long long*)alloc((size_t)NIMG * NLV * 16 * 1024 * 8);
    (void)ws_size; (void)n_in;

    k_hist<<<dim3(NHB, NLV, NIMG), 256, 0, stream>>>(P, hist);
    k_thresh<<<NIMG * NLV, 1024, 0, stream>>>(hist, thr, scnt, tcnt);
    k_pick<<<dim3(PBLK, NLV, NIMG), 256, 0, stream>>>(P, thr, scnt, tcnt, cg, cl, tiebuf);
    k_tie<<<NIMG * NLV, 1024, 0, stream>>>(thr, tcnt, tiebuf, cg, cl);
    k_build<<<(NIMG * NLV * 1024) / 256, 256, 0, stream>>>(P, cg, cl, pkey, pbox, pbn, plog);
    k_sortL<<<NIMG * NLV, 512, 0, stream>>>(pkey, pbox, pbn, plog, skey, sboxL, cboxL, slogL, ccnt);
    k_mask<<<dim3(256, NLV, NIMG), 256, 0, stream>>>(cboxL, ccnt, MT);
    k_scan<<<dim3(NLV, NIMG), 1024, 0, stream>>>(MT, ccnt, keepL);
    k_rank<<<NIMG, 1024, 0, stream>>>(skey, keepL, ccnt, sboxL, slogL, (float*)d_out);
}